// Round 8
// baseline (789.988 us; speedup 1.0000x reference)
//
#include <hip/hip_runtime.h>

#define N_NODES 100000
#define N_EDGES 1600000
#define EMBED_DIM 64

#define RPB 128                                    // rows per bucket
#define NBKT ((N_NODES + RPB - 1) / RPB)           // 782
#define TILE 4096                                  // edges per binA tile
#define NTILE ((N_EDGES + TILE - 1) / TILE)        // 391
#define DIRW (NBKT + 1)                            // 783 (with per-tile sentinel)
#define ECAP 2432                                  // bucket mean 2046, +8.5 sigma

// ---------- pass 0: X fp32 -> bf16 (RNE) ----------
__global__ __launch_bounds__(256) void k_xcast(const float* __restrict__ x,
                                               unsigned short* __restrict__ xb) {
    int i = blockIdx.x * 256 + threadIdx.x;  // float4 index
    const int n4 = N_NODES * EMBED_DIM / 4;
    if (i >= n4) return;
    float4 f = ((const float4*)x)[i];
    unsigned b0 = __float_as_uint(f.x), b1 = __float_as_uint(f.y);
    unsigned b2 = __float_as_uint(f.z), b3 = __float_as_uint(f.w);
    ushort4 h;
    h.x = (unsigned short)((b0 + 0x7FFFu + ((b0 >> 16) & 1)) >> 16);
    h.y = (unsigned short)((b1 + 0x7FFFu + ((b1 >> 16) & 1)) >> 16);
    h.z = (unsigned short)((b2 + 0x7FFFu + ((b2 >> 16) & 1)) >> 16);
    h.w = (unsigned short)((b3 + 0x7FFFu + ((b3 >> 16) & 1)) >> 16);
    ((ushort4*)xb)[i] = h;
}

// ---------- pass 1: per-tile counting sort by bucket; LINEAR dense flush ----------
// No global atomics: tile t's edges land at packed[t*TILE ...], grouped by
// bucket; dir[t][b] = global start of (t,b) segment, dir[t][NBKT] = sentinel.
__global__ __launch_bounds__(512) void k_binA(const int* __restrict__ rows,
                                              const int* __restrict__ cols,
                                              const float* __restrict__ vals,
                                              int2* __restrict__ packed,
                                              int* __restrict__ dir) {
    __shared__ int hist[NBKT];
    __shared__ int cur[NBKT];
    __shared__ int ssum[512];
    __shared__ int2 stage[TILE];   // 32 KB
    const int tid = threadIdx.x;
    const int t = blockIdx.x;
    const int e0 = t * TILE;
    const int nt = (N_EDGES - e0 < TILE) ? (N_EDGES - e0) : TILE;

    for (int i = tid; i < NBKT; i += 512) hist[i] = 0;
    __syncthreads();

    for (int i = tid; i < nt; i += 512) atomicAdd(&hist[rows[e0 + i] >> 7], 1);
    __syncthreads();

    // exclusive scan over 782 buckets (2 per thread)
    int b0 = 2 * tid, b1 = 2 * tid + 1;
    int h0 = (b0 < NBKT) ? hist[b0] : 0;
    int h1 = (b1 < NBKT) ? hist[b1] : 0;
    ssum[tid] = h0 + h1;
    __syncthreads();
    for (int o = 1; o < 512; o <<= 1) {
        int a = ssum[tid];
        int add = (tid >= o) ? ssum[tid - o] : 0;
        __syncthreads();
        ssum[tid] = a + add;
        __syncthreads();
    }
    int base = (tid == 0) ? 0 : ssum[tid - 1];
    if (b0 < NBKT) { cur[b0] = base;      dir[t * DIRW + b0] = e0 + base; }
    if (b1 < NBKT) { cur[b1] = base + h0; dir[t * DIRW + b1] = e0 + base + h0; }
    if (tid == 0) dir[t * DIRW + NBKT] = e0 + nt;
    __syncthreads();

    // placement: group by bucket in LDS
    for (int i = tid; i < nt; i += 512) {
        int e = e0 + i;
        int r = rows[e];
        int p = atomicAdd(&cur[r >> 7], 1);
        stage[p] = make_int2(((r & (RPB - 1)) << 17) | cols[e],
                             __float_as_int(vals[e]));
    }
    __syncthreads();

    // linear flush: fully dense, coalesced
    for (int j = tid; j < nt; j += 512) packed[e0 + j] = stage[j];
}

// ---------- pass 2: one block per bucket; flat compaction, accumulate ----------
__global__ __launch_bounds__(512) void k_accum(const unsigned short* __restrict__ xb,
                                               const int* __restrict__ dir,
                                               const int2* __restrict__ packed,
                                               float* __restrict__ out) {
    __shared__ float acc[RPB * EMBED_DIM];  // 32 KB
    __shared__ int2 est[ECAP];              // 19 KB
    __shared__ int scnt[NTILE];
    __shared__ int soff[NTILE];
    __shared__ int sstart[NTILE];
    __shared__ int ssum[512];
    const int tid = threadIdx.x;
    const int b = blockIdx.x;

    for (int i = tid; i < RPB * EMBED_DIM; i += 512) acc[i] = 0.f;

    // segment meta: adjacent-pair read per tile
    if (tid < NTILE) {
        int s = dir[tid * DIRW + b];
        int e = dir[tid * DIRW + b + 1];
        sstart[tid] = s;
        scnt[tid] = e - s;
    }
    __syncthreads();

    // block scan of segment counts
    int c = (tid < NTILE) ? scnt[tid] : 0;
    ssum[tid] = c;
    __syncthreads();
    for (int o = 1; o < 512; o <<= 1) {
        int a = ssum[tid];
        int add = (tid >= o) ? ssum[tid - o] : 0;
        __syncthreads();
        ssum[tid] = a + add;
        __syncthreads();
    }
    int total = ssum[511];
    if (tid < NTILE) soff[tid] = ssum[tid] - c;
    __syncthreads();

    // flat compaction: thread j binary-searches its tile, loads its edge.
    // All 512 lanes issue loads each round; consecutive j -> consecutive src.
    for (int j = tid; j < total; j += 512) {
        int lo = 0, hi = NTILE - 1;
        while (lo < hi) {
            int mid = (lo + hi + 1) >> 1;
            if (soff[mid] <= j) lo = mid; else hi = mid - 1;
        }
        int2 ed = packed[sstart[lo] + (j - soff[lo])];
        if (j < ECAP) {
            est[j] = ed;
        } else {  // statistically-never slow path (correct for any input)
            int col = ed.x & 0x1FFFF;
            int lr  = ((unsigned)ed.x) >> 17;
            float v = __int_as_float(ed.y);
            for (int q = 0; q < EMBED_DIM; ++q) {
                float xv = __uint_as_float((unsigned)xb[col * EMBED_DIM + q] << 16);
                atomicAdd(&acc[lr * EMBED_DIM + q], v * xv);
            }
        }
    }
    __syncthreads();

    int n = (total < ECAP) ? total : ECAP;
    const int w = tid >> 6, lane = tid & 63;

    // main rounds: 8 waves x 8-deep unroll -> 8 bf16 gather loads in flight
    int e8 = w * 8;
    for (; e8 + 8 <= n; e8 += 64) {
        int2 ed[8];
#pragma unroll
        for (int k = 0; k < 8; ++k) ed[k] = est[e8 + k];  // LDS broadcast
        float xv[8];
#pragma unroll
        for (int k = 0; k < 8; ++k)
            xv[k] = __uint_as_float(
                (unsigned)xb[(ed[k].x & 0x1FFFF) * EMBED_DIM + lane] << 16);
#pragma unroll
        for (int k = 0; k < 8; ++k)
            atomicAdd(&acc[(((unsigned)ed[k].x) >> 17) * EMBED_DIM + lane],
                      __int_as_float(ed[k].y) * xv[k]);
    }
    // tail (<8 edges), wave 0 only
    if (w == 0) {
        for (int idx = n & ~7; idx < n; ++idx) {
            int2 ed = est[idx];
            float xv = __uint_as_float(
                (unsigned)xb[(ed.x & 0x1FFFF) * EMBED_DIM + lane] << 16);
            atomicAdd(&acc[(((unsigned)ed.x) >> 17) * EMBED_DIM + lane],
                      __int_as_float(ed.y) * xv);
        }
    }
    __syncthreads();

    // dense output write: 128 rows x 64 dims as float4
    const int r0 = b * RPB;
    float4* o4 = (float4*)out;
    const float4* a4 = (const float4*)acc;
    for (int i = tid; i < RPB * EMBED_DIM / 4; i += 512) {
        int r = r0 + (i >> 4);
        if (r < N_NODES) o4[(size_t)r * 16 + (i & 15)] = a4[i];
    }
}

// ---------- fallback (ws too small): atomic scatter ----------
__global__ __launch_bounds__(256) void spmm_scatter_kernel(
    const float* __restrict__ x, const float* __restrict__ vals,
    const int* __restrict__ rows, const int* __restrict__ cols,
    float* __restrict__ out) {
    const int wave_in_block = threadIdx.x >> 6;
    const int lane = threadIdx.x & 63;
    const int e = blockIdx.x * 4 + wave_in_block;
    if (e >= N_EDGES) return;
    const float m = vals[e] * x[cols[e] * EMBED_DIM + lane];
    atomicAdd(&out[rows[e] * EMBED_DIM + lane], m);
}

extern "C" void kernel_launch(void* const* d_in, const int* in_sizes, int n_in,
                              void* d_out, int out_size, void* d_ws, size_t ws_size,
                              hipStream_t stream) {
    const float* x    = (const float*)d_in[0];
    const float* vals = (const float*)d_in[1];
    const int*   rows = (const int*)d_in[2];
    const int*   cols = (const int*)d_in[3];
    float* out = (float*)d_out;

    // ws: packed int2[NTILE*TILE] | dir int[NTILE*DIRW] | xb ushort[N*64]
    const size_t packed_b = (size_t)NTILE * TILE * 8;        // 12,812,288
    const size_t dir_b    = (size_t)NTILE * DIRW * 4;        //  1,224,612
    const size_t xb_b     = (size_t)N_NODES * EMBED_DIM * 2; // 12,800,000
    const size_t need = packed_b + dir_b + xb_b;             // ~26.8 MB

    if (ws_size < need) {
        hipMemsetAsync(out, 0, (size_t)out_size * sizeof(float), stream);
        spmm_scatter_kernel<<<(N_EDGES + 3) / 4, 256, 0, stream>>>(x, vals, rows, cols, out);
        return;
    }

    int2* packed = (int2*)d_ws;
    int*  dir    = (int*)((char*)d_ws + packed_b);
    unsigned short* xbuf = (unsigned short*)((char*)d_ws + packed_b + dir_b);

    k_xcast<<<(N_NODES * EMBED_DIM / 4 + 255) / 256, 256, 0, stream>>>(x, xbuf);
    k_binA<<<NTILE, 512, 0, stream>>>(rows, cols, vals, packed, dir);
    k_accum<<<NBKT, 512, 0, stream>>>(xbuf, dir, packed, out);
}

// Round 9
// 207.061 us; speedup vs baseline: 3.8152x; 3.8152x over previous
//
#include <hip/hip_runtime.h>

#define N_NODES 100000
#define N_EDGES 1600000
#define EMBED_DIM 64

#define RPB 128                                    // rows per bucket
#define NBKT ((N_NODES + RPB - 1) / RPB)           // 782
#define CAP 2432                                   // bucket slots: mean 2046 + 8.5 sigma
#define TILE 2048                                  // edges per binA block
#define NTILE ((N_EDGES + TILE - 1) / TILE)        // 782
#define OVCAP 8192                                 // overflow backstop

// ---------- pass 0: X fp32 -> bf16 (RNE) ----------
__global__ __launch_bounds__(256) void k_xcast(const float* __restrict__ x,
                                               unsigned short* __restrict__ xb) {
    int i = blockIdx.x * 256 + threadIdx.x;  // float4 index
    const int n4 = N_NODES * EMBED_DIM / 4;
    if (i >= n4) return;
    float4 f = ((const float4*)x)[i];
    unsigned b0 = __float_as_uint(f.x), b1 = __float_as_uint(f.y);
    unsigned b2 = __float_as_uint(f.z), b3 = __float_as_uint(f.w);
    ushort4 h;
    h.x = (unsigned short)((b0 + 0x7FFFu + ((b0 >> 16) & 1)) >> 16);
    h.y = (unsigned short)((b1 + 0x7FFFu + ((b1 >> 16) & 1)) >> 16);
    h.z = (unsigned short)((b2 + 0x7FFFu + ((b2 >> 16) & 1)) >> 16);
    h.w = (unsigned short)((b3 + 0x7FFFu + ((b3 >> 16) & 1)) >> 16);
    ((ushort4*)xb)[i] = h;
}

// ---------- pass 1: stageless bucket append ----------
// LDS hist -> one reservation atomic per non-empty bucket -> direct global
// append. Only ~782 bucket-tail lines are partially dirty at any time (~100 KB,
// L2-resident), so writeback is dense despite the scattered 8B stores.
__global__ __launch_bounds__(256) void k_binA(const int* __restrict__ rows,
                                              const int* __restrict__ cols,
                                              const float* __restrict__ vals,
                                              int* __restrict__ gcur,
                                              int2* __restrict__ packed,
                                              int* __restrict__ ov_cnt,
                                              int4* __restrict__ ov) {
    __shared__ int hist[NBKT];
    __shared__ int cur[NBKT];
    const int tid = threadIdx.x;
    const int e0 = blockIdx.x * TILE;
    const int nt = (N_EDGES - e0 < TILE) ? (N_EDGES - e0) : TILE;

    for (int i = tid; i < NBKT; i += 256) hist[i] = 0;
    __syncthreads();
    for (int i = tid; i < nt; i += 256) atomicAdd(&hist[rows[e0 + i] >> 7], 1);
    __syncthreads();
    for (int b = tid; b < NBKT; b += 256) {
        int c = hist[b];
        if (c) cur[b] = atomicAdd(&gcur[b], c);   // bucket-relative base
    }
    __syncthreads();
    for (int i = tid; i < nt; i += 256) {
        int e = e0 + i;
        int r = rows[e];
        int b = r >> 7;
        int c = cols[e];
        int ls = atomicAdd(&cur[b], 1);
        if (ls < CAP) {
            packed[b * CAP + ls] = make_int2(((r & (RPB - 1)) << 17) | c,
                                             __float_as_int(vals[e]));
        } else {  // statistically-never overflow (kept for arbitrary inputs)
            int ovi = atomicAdd(ov_cnt, 1);
            if (ovi < OVCAP) ov[ovi] = make_int4(r, c, __float_as_int(vals[e]), 0);
        }
    }
}

// ---------- pass 2: per-bucket row-sort (in-place via LDS stage), emit CSR ----------
__global__ __launch_bounds__(256) void k_binB(const int* __restrict__ gcur,
                                              int2* __restrict__ packed,
                                              int* __restrict__ row_ptr,
                                              int* __restrict__ cnt) {
    __shared__ int2 stage[CAP];          // 19 KB
    __shared__ int h[RPB], s[RPB], cur[RPB];
    const int b = blockIdx.x;
    const int tid = threadIdx.x;
    int n = gcur[b];
    if (n > CAP) n = CAP;
    const int base = b * CAP;

    if (tid < RPB) h[tid] = 0;
    __syncthreads();
    for (int j = tid; j < n; j += 256) {
        int2 e = packed[base + j];
        stage[j] = e;
        atomicAdd(&h[((unsigned)e.x) >> 17], 1);
    }
    __syncthreads();

    int hv = 0;
    if (tid < RPB) { hv = h[tid]; s[tid] = hv; }
    __syncthreads();
    for (int o = 1; o < RPB; o <<= 1) {
        int add = 0;
        if (tid < RPB && tid >= o) add = s[tid - o];
        __syncthreads();
        if (tid < RPB && tid >= o) s[tid] += add;
        __syncthreads();
    }
    if (tid < RPB) {
        int ofs = s[tid] - hv;           // exclusive
        cur[tid] = ofs;
        int r = b * RPB + tid;
        if (r < N_NODES) { row_ptr[r] = base + ofs; cnt[r] = hv; }
    }
    __syncthreads();

    for (int j = tid; j < n; j += 256) {
        int2 e = stage[j];
        int p = atomicAdd(&cur[((unsigned)e.x) >> 17], 1);
        packed[base + p] = make_int2(e.x & 0x1FFFF, e.y);   // strip lrow
    }
}

// ---------- pass 3: one wave per row; scalar edge loads + bf16 gather ----------
__global__ __launch_bounds__(256) void k_gather_bf16(
    const unsigned short* __restrict__ xb,
    const int* __restrict__ row_ptr, const int* __restrict__ cnt,
    const int2* __restrict__ ep, float* __restrict__ out) {
    int wid = (blockIdx.x * 256 + threadIdx.x) >> 6;
    int lane = threadIdx.x & 63;
    if (wid >= N_NODES) return;
    int beg = __builtin_amdgcn_readfirstlane(row_ptr[wid]);
    int deg = __builtin_amdgcn_readfirstlane(cnt[wid]);
    const int2* p = ep + beg;
    float acc = 0.f;
    int k = 0;
    for (; k + 8 <= deg; k += 8) {
        int2 e[8];
#pragma unroll
        for (int i = 0; i < 8; ++i) e[i] = p[k + i];    // scalar s_load
        float xv[8];
#pragma unroll
        for (int i = 0; i < 8; ++i)
            xv[i] = __uint_as_float((unsigned)xb[(e[i].x << 6) + lane] << 16);
#pragma unroll
        for (int i = 0; i < 8; ++i) acc += __int_as_float(e[i].y) * xv[i];
    }
    for (; k < deg; ++k) {
        int2 e = p[k];
        acc += __int_as_float(e.y) *
               __uint_as_float((unsigned)xb[(e.x << 6) + lane] << 16);
    }
    out[wid * EMBED_DIM + lane] = acc;
}

// ---------- fp32 gather (mid path when ws can't fit xb) ----------
__global__ __launch_bounds__(256) void k_gather_f32(
    const float* __restrict__ x,
    const int* __restrict__ row_ptr, const int* __restrict__ cnt,
    const int2* __restrict__ ep, float* __restrict__ out) {
    int wid = (blockIdx.x * 256 + threadIdx.x) >> 6;
    int lane = threadIdx.x & 63;
    if (wid >= N_NODES) return;
    int beg = __builtin_amdgcn_readfirstlane(row_ptr[wid]);
    int deg = __builtin_amdgcn_readfirstlane(cnt[wid]);
    const int2* p = ep + beg;
    float acc = 0.f;
    int k = 0;
    for (; k + 8 <= deg; k += 8) {
        int2 e[8];
#pragma unroll
        for (int i = 0; i < 8; ++i) e[i] = p[k + i];
        float xv[8];
#pragma unroll
        for (int i = 0; i < 8; ++i) xv[i] = x[(e[i].x << 6) + lane];
#pragma unroll
        for (int i = 0; i < 8; ++i) acc += __int_as_float(e[i].y) * xv[i];
    }
    for (; k < deg; ++k) {
        int2 e = p[k];
        acc += __int_as_float(e.y) * x[(e.x << 6) + lane];
    }
    out[wid * EMBED_DIM + lane] = acc;
}

// ---------- overflow cleanup (expected n==0; exact fp32) ----------
__global__ __launch_bounds__(256) void k_overflow(const float* __restrict__ x,
                                                  const int* __restrict__ ov_cnt,
                                                  const int4* __restrict__ ov,
                                                  float* __restrict__ out) {
    int n = *ov_cnt;
    if (n > OVCAP) n = OVCAP;
    int lane = threadIdx.x & 63;
    for (int idx = (blockIdx.x * 256 + threadIdx.x) >> 6; idx < n;
         idx += gridDim.x * 4) {
        int4 e = ov[idx];
        atomicAdd(&out[e.x * EMBED_DIM + lane],
                  __int_as_float(e.z) * x[e.y * EMBED_DIM + lane]);
    }
}

// ---------- fallback (ws too small): atomic scatter ----------
__global__ __launch_bounds__(256) void spmm_scatter_kernel(
    const float* __restrict__ x, const float* __restrict__ vals,
    const int* __restrict__ rows, const int* __restrict__ cols,
    float* __restrict__ out) {
    const int wave_in_block = threadIdx.x >> 6;
    const int lane = threadIdx.x & 63;
    const int e = blockIdx.x * 4 + wave_in_block;
    if (e >= N_EDGES) return;
    const float m = vals[e] * x[cols[e] * EMBED_DIM + lane];
    atomicAdd(&out[rows[e] * EMBED_DIM + lane], m);
}

extern "C" void kernel_launch(void* const* d_in, const int* in_sizes, int n_in,
                              void* d_out, int out_size, void* d_ws, size_t ws_size,
                              hipStream_t stream) {
    const float* x    = (const float*)d_in[0];
    const float* vals = (const float*)d_in[1];
    const int*   rows = (const int*)d_in[2];
    const int*   cols = (const int*)d_in[3];
    float* out = (float*)d_out;

    // ws: packed int2[NBKT*CAP] | xb ushort[N*64]? | ov int4[OVCAP] |
    //     gcur[NBKT] | ov_cnt | row_ptr[N] | cnt[N]
    const size_t packed_b = (size_t)NBKT * CAP * 8;          // 15,214,592
    const size_t xb_b     = (size_t)N_NODES * EMBED_DIM * 2; // 12,800,000
    const size_t ov_b     = (size_t)OVCAP * 16;              //    131,072
    const size_t tail_b   = ((size_t)NBKT + 1 + 2 * (size_t)N_NODES) * 4;
    const size_t need_full = packed_b + xb_b + ov_b + tail_b;  // ~28.9 MB
    const size_t need_mid  = packed_b + ov_b + tail_b;         // ~16.1 MB

    if (ws_size < need_mid) {
        hipMemsetAsync(out, 0, (size_t)out_size * sizeof(float), stream);
        spmm_scatter_kernel<<<(N_EDGES + 3) / 4, 256, 0, stream>>>(x, vals, rows, cols, out);
        return;
    }
    const bool use_bf16 = (ws_size >= need_full);

    int2* packed = (int2*)d_ws;
    char* cursor_p = (char*)d_ws + packed_b;
    unsigned short* xbuf = (unsigned short*)cursor_p;
    if (use_bf16) cursor_p += xb_b;
    int4* ov     = (int4*)cursor_p;
    int*  gcur   = (int*)(cursor_p + ov_b);
    int*  ov_cnt = gcur + NBKT;
    int*  row_ptr = ov_cnt + 1;
    int*  cnt     = row_ptr + N_NODES;

    hipMemsetAsync(gcur, 0, ((size_t)NBKT + 1) * sizeof(int), stream);  // gcur + ov_cnt

    if (use_bf16)
        k_xcast<<<(N_NODES * EMBED_DIM / 4 + 255) / 256, 256, 0, stream>>>(x, xbuf);
    k_binA<<<NTILE, 256, 0, stream>>>(rows, cols, vals, gcur, packed, ov_cnt, ov);
    k_binB<<<NBKT, 256, 0, stream>>>(gcur, packed, row_ptr, cnt);
    if (use_bf16)
        k_gather_bf16<<<(N_NODES * 64 + 255) / 256, 256, 0, stream>>>(xbuf, row_ptr, cnt, packed, out);
    else
        k_gather_f32<<<(N_NODES * 64 + 255) / 256, 256, 0, stream>>>(x, row_ptr, cnt, packed, out);
    k_overflow<<<64, 256, 0, stream>>>(x, ov_cnt, ov, out);
}